// Round 12
// baseline (181.384 us; speedup 1.0000x reference)
//
#include <hip/hip_runtime.h>
#include <hip/hip_bf16.h>

// CRF log-likelihood, MI355X. SEQ=512, B=1024, T=48.
// One wave per batch chain (1024 waves). State-as-A MFMA with REPLICATED rows:
// A[row][k] = y[k] for all rows -> C[row][col] = q'_col in every lane. Repack
// per step: y-mul (3) -> pub[l]=y[l] (2 cndmask) -> ONE batch of 16 bperm
// (addr = k*4, canonical publish) -> 8 cvt_pk -> 6 MFMA. B = exp(trans) frags
// (k>=48 rows zero). Per-group exact power-of-2 renorm folded into w; integer
// log2 bookkeeping. Numerator chunk-parallel (R7-verbatim). Emissions
// double-buffered via global_load_lds. Loops: chunk/group unroll-1, 8-step
// body unrolled (I-cache resident). Fragment layouts HW-verified (R5/R10
// absmax 0.0): A[row=l&15][k=8*(l>>4)+e] pairs (2d,2d+1)/reg; B[k][col=l&15];
// C col=l&15, row=4*(l>>4)+reg.

constexpr int SEQ = 512, BN = 1024, TT = 48;
constexpr int CH = 64, NCH = SEQ / CH;
#define LOG2E 1.44269504088896340736f
#define LN2   0.69314718055994530942f

typedef float f32x4 __attribute__((ext_vector_type(4)));
typedef short s16x8 __attribute__((ext_vector_type(8)));
typedef int   s32x4 __attribute__((ext_vector_type(4)));
typedef unsigned short u16;

__device__ __forceinline__ float fexp2(float x){ return __builtin_amdgcn_exp2f(x); }
__device__ __forceinline__ float flog2(float x){ return __builtin_amdgcn_logf(x); }
__device__ __forceinline__ float rlane0(float v){
    return __int_as_float(__builtin_amdgcn_readlane(__float_as_int(v), 0));
}
__device__ __forceinline__ float bpermf(int addr, float src){
    return __int_as_float(__builtin_amdgcn_ds_bpermute(addr, __float_as_int(src)));
}
__device__ __forceinline__ int cvtpk(float lo, float hi){
    int r;
    asm("v_cvt_pk_bf16_f32 %0, %1, %2" : "=v"(r) : "v"(lo), "v"(hi));
    return r;
}
__device__ __forceinline__ u16 f2bf(float f){
    __hip_bfloat16 h = __float2bfloat16(f);
    return __builtin_bit_cast(u16, h);
}
__device__ __forceinline__ f32x4 MFMA(s32x4 a, s32x4 b, f32x4 c){
    return __builtin_amdgcn_mfma_f32_16x16x32_bf16(
        __builtin_bit_cast(s16x8, a), __builtin_bit_cast(s16x8, b), c, 0, 0, 0);
}

__global__ __launch_bounds__(64, 1) void crf_fwd(
    const float* __restrict__ emis, const int* __restrict__ tags,
    const int* __restrict__ mask, const float* __restrict__ start_t,
    const float* __restrict__ end_t, const float* __restrict__ trans,
    float* __restrict__ ws)
{
    __shared__ float ltr[TT * TT];
    __shared__ __align__(16) float ebuf[2][CH * TT];  // 2 x 12 KB

    const int lane = threadIdx.x;
    const int b = blockIdx.x;
    const int g  = lane >> 4;       // k-slice group 0..3
    const int cl = lane & 15;       // col 0..15
    const bool jv = (lane < TT);
    const int jc = jv ? lane : (TT - 1);

    // staging offsets (16B per lane per instr)
    int offs[12];
#pragma unroll
    for (int k = 0; k < 12; ++k) {
        const int gg = k * 64 + lane;
        const int r = gg / 12, j4 = gg % 12;
        offs[k] = r * (BN * TT * 4) + j4 * 16;
    }

#define STAGE_CHUNK(tb, buf)                                                   \
    {                                                                          \
        const char* cb = (const char*)emis + ((size_t)(tb) * BN + b) * (TT * 4); \
        _Pragma("unroll")                                                      \
        for (int k = 0; k < 12; ++k) {                                         \
            __builtin_amdgcn_global_load_lds(                                  \
                (const __attribute__((address_space(1))) void*)(cb + offs[k]), \
                (__attribute__((address_space(3))) void*)(&ebuf[buf][k * 256]),\
                16, 0, 0);                                                     \
        }                                                                      \
    }

    // ---- prologue ----
    STAGE_CHUNK(0, 0);
    int tgv = tags[(size_t)lane * BN + b];
    int mkv = mask[(size_t)lane * BN + b];
    const int tag0 = tags[b];

    for (int i = lane; i < TT * TT; i += 64) ltr[i] = trans[i];
    __syncthreads();  // also orders LDS fill; staged chunk drained below

    // B = exp(trans) fragments: B[k = 32kt + 8g + e][col = 16n + cl], k>=48 -> 0
    s32x4 B00, B01, B02, B10, B11, B12;
    {
        s32x4 tmpf[6];
#pragma unroll
        for (int n = 0; n < 3; ++n)
#pragma unroll
            for (int kt = 0; kt < 2; ++kt) {
                u16 tmp[8];
#pragma unroll
                for (int e = 0; e < 8; ++e) {
                    const int k = 32 * kt + 8 * g + e;
                    float x = 0.0f;
                    if (k < TT) x = fexp2(ltr[k * TT + 16 * n + cl] * LOG2E);
                    tmp[e] = f2bf(x);
                }
                s32x4 fr;
#pragma unroll
                for (int d = 0; d < 4; ++d)
                    fr[d] = (int)((unsigned)tmp[2 * d] | ((unsigned)tmp[2 * d + 1] << 16));
                tmpf[n * 2 + kt] = fr;
            }
        B00 = tmpf[0]; B10 = tmpf[1];
        B01 = tmpf[2]; B11 = tmpf[3];
        B02 = tmpf[4]; B12 = tmpf[5];
    }

    const float st = start_t[jc];
    const float en = end_t[jc];
    const int ab = g * 32;  // byte base for A-gather (k = 8g -> bytes 32g)

    asm volatile("s_waitcnt vmcnt(0)" ::: "memory");
    __builtin_amdgcn_sched_barrier(0);

    // ---- init state (t=0): pub[l] = y[l] = exp(st_l + e0_l)*2^-6 ----
    const float e00 = ebuf[0][jc];
    float pub = jv ? fexp2(fmaf(st + e00, LOG2E, -6.0f)) : 0.0f;
    int la = 6;

    // gather A frags from pub (replicated rows)
    s32x4 A0, A1;
#pragma unroll
    for (int d = 0; d < 4; ++d) {
        A0[d] = cvtpk(bpermf(ab + 8 * d, pub), bpermf(ab + 8 * d + 4, pub));
        const int p = cvtpk(bpermf(128 + ab + 8 * d, pub), bpermf(128 + ab + 8 * d + 4, pub));
        A1[d] = (g < 2) ? p : 0;
    }

    // numerator init
    float numpart = (lane == tag0) ? (st + e00) : 0.f;
    float numtr = 0.f, numem = 0.f;
    int mcount = 0;
    int carry_tag = tag0;

    STAGE_CHUNK(CH, 1);
    int tgn = tags[((size_t)CH + lane) * BN + b];
    int mkn = mask[((size_t)CH + lane) * BN + b];

    // initial C = q' for step 1
    const f32x4 z = {0.f, 0.f, 0.f, 0.f};
    f32x4 c0 = MFMA(A0, B00, z); c0 = MFMA(A1, B10, c0);
    f32x4 c1 = MFMA(A0, B01, z); c1 = MFMA(A1, B11, c1);
    f32x4 c2 = MFMA(A0, B02, z); c2 = MFMA(A1, B12, c2);

    int cur = 0;

#pragma unroll 1
    for (int ch = 0; ch < NCH; ++ch) {
        const int tbase = ch * CH;
        const float* ebc = ebuf[cur];

        // ---- chunk-parallel numerator + commit word (off the serial chain) ----
        const int tmv = (mkv && (tbase + lane) > 0) ? tgv : -1;
        const unsigned long long vmword = __ballot(tmv >= 0);
        int tprev = __shfl_up(tgv, 1, 64);
        if (lane == 0) tprev = carry_tag;
        if (tmv >= 0) {
            numtr += ltr[tprev * TT + tgv];
            numem += ebc[lane * TT + tgv];
        }
        carry_tag = __builtin_amdgcn_readlane(tgv, 63);
        mcount += __popcll(__ballot(mkv != 0));
        la += 6 * (int)__popcll(vmword);

        // emission prefetch for ts=0 (cols 16n+cl)
        float ea0 = ebc[cl], ea1 = ebc[16 + cl], ea2 = ebc[32 + cl];

        // ---- 8 groups x 8 serial MFMA steps ----
#pragma unroll 1
        for (int sc = 0; sc < 8; ++sc) {
            const unsigned gm = (unsigned)(vmword >> (sc * 8)) & 0xFFu;

#pragma unroll
            for (int u = 0; u < 8; ++u) {
                const int ts = sc * 8 + u;
                const int tsn = (ts + 1 < CH) ? (ts + 1) : (CH - 1);
                // prefetch next step's emissions (off-chain)
                const float eb0 = ebc[tsn * TT + cl];
                const float eb1 = ebc[tsn * TT + 16 + cl];
                const float eb2 = ebc[tsn * TT + 32 + cl];

                if ((gm >> u) & 1u) {  // uniform branch
                    float w0 = fexp2(fmaf(ea0, LOG2E, -6.0f));
                    float w1 = fexp2(fmaf(ea1, LOG2E, -6.0f));
                    float w2 = fexp2(fmaf(ea2, LOG2E, -6.0f));
                    if (u == 0) {  // per-group renorm: exact power-of-2
                        const float q0 = rlane0(c0[0]);
                        const int m = ((__float_as_int(q0) >> 23) & 0xFF) - 127;
                        const float scl = __int_as_float((127 - m) << 23);
                        la += m;
                        w0 *= scl; w1 *= scl; w2 *= scl;
                    }
                    // y_j = q'_j * w_j at this lane's three cols
                    const float y0 = c0[0] * w0;
                    const float y1 = c1[0] * w1;
                    const float y2 = c2[0] * w2;
                    // canonical publish: pub[l] = y[l]  (component g of col cl)
                    pub = (g == 0) ? y0 : ((g == 1) ? y1 : y2);
                    // ONE parallel batch of 16 bperm -> next A frags
#pragma unroll
                    for (int d = 0; d < 4; ++d) {
                        A0[d] = cvtpk(bpermf(ab + 8 * d, pub),
                                      bpermf(ab + 8 * d + 4, pub));
                        const int p = cvtpk(bpermf(128 + ab + 8 * d, pub),
                                            bpermf(128 + ab + 8 * d + 4, pub));
                        A1[d] = (g < 2) ? p : 0;
                    }
                    // q_next = state @ E  (3 independent MFMA pairs)
                    c0 = MFMA(A0, B00, z); c0 = MFMA(A1, B10, c0);
                    c1 = MFMA(A0, B01, z); c1 = MFMA(A1, B11, c1);
                    c2 = MFMA(A0, B02, z); c2 = MFMA(A1, B12, c2);
                }
                ea0 = eb0; ea1 = eb1; ea2 = eb2;
            }
        }

        // ---- chunk boundary: drain staged loads, swap buffers ----
        asm volatile("s_waitcnt vmcnt(0)" ::: "memory");
        __builtin_amdgcn_sched_barrier(0);
        cur ^= 1;
        tgv = tgn; mkv = mkn;
        if (ch + 2 < NCH) {
            STAGE_CHUNK(tbase + 2 * CH, cur ^ 1);
            tgn = tags[((size_t)(tbase + 2 * CH) + lane) * BN + b];
            mkn = mask[((size_t)(tbase + 2 * CH) + lane) * BN + b];
        }
    }

    // ---- numerator tail ----
    const int last_tag = tags[(size_t)(mcount - 1) * BN + b];  // uniform
    numpart += (lane == last_tag) ? en : 0.f;
    numpart += numtr + numem;

    // ---- denominator: pub[l] = last committed y[l] (f32 shadow) ----
    float v = jv ? (pub * fexp2(en * LOG2E)) : 0.0f;
    float se = v;
#pragma unroll
    for (int d = 1; d < 64; d <<= 1)
        se += __shfl_xor(se, d, 64);
    const float den = (flog2(se) + (float)la) * LN2;

    float num = numpart;
#pragma unroll
    for (int d = 1; d < 64; d <<= 1)
        num += __shfl_xor(num, d, 64);

    if (lane == 0) ws[b] = num - den;
#undef STAGE_CHUNK
}

__global__ __launch_bounds__(256) void reduce_mean(
    const float* __restrict__ ws, float* __restrict__ out)
{
    const int tid = threadIdx.x;
    float v = ws[tid] + ws[tid + 256] + ws[tid + 512] + ws[tid + 768];
#pragma unroll
    for (int d = 1; d < 64; d <<= 1)
        v += __shfl_xor(v, d, 64);
    __shared__ float acc[4];
    if ((tid & 63) == 0) acc[tid >> 6] = v;
    __syncthreads();
    if (tid == 0) out[0] = (acc[0] + acc[1] + acc[2] + acc[3]) * (1.f / 1024.f);
}

extern "C" void kernel_launch(void* const* d_in, const int* in_sizes, int n_in,
                              void* d_out, int out_size, void* d_ws, size_t ws_size,
                              hipStream_t stream)
{
    const float* emis    = (const float*)d_in[0];
    const int*   tags    = (const int*)d_in[1];
    const int*   mask    = (const int*)d_in[2];
    const float* start_t = (const float*)d_in[3];
    const float* end_t   = (const float*)d_in[4];
    const float* trans   = (const float*)d_in[5];
    float* ws  = (float*)d_ws;
    float* out = (float*)d_out;

    crf_fwd<<<dim3(BN), dim3(64), 0, stream>>>(emis, tags, mask, start_t, end_t, trans, ws);
    reduce_mean<<<dim3(1), dim3(256), 0, stream>>>(ws, out);
}

// Round 13
// 106.196 us; speedup vs baseline: 1.7080x; 1.7080x over previous
//
#include <hip/hip_runtime.h>

// CRF log-likelihood, MI355X. SEQ=512, B=1024, T=48.
// SEQUENCE-PARALLEL x2: seg0 = t[0,256), seg1 = warm-up t[224,256) from
// uniform state (Birkhoff contraction ~10x/step -> fp32-exact after 32) then
// t[256,512). 2048 waves = 2 waves/SIMD so each wave's dependent-latency
// stalls hide under the other's issue. Linear-domain recurrence (R7 body):
// r <- (r @ E)*exp(e)*2^-6, E=exp(trans) in 48 VGPRs, readlane+fmac matvec,
// exact power-of-2 renorm per 8-step group, integer log2 bookkeeping.
// Log-domain stitch: den = A + B - W1 (exact). LDS = 12.3 KB (CH=32, trans
// from global) so 8 blocks/CU co-reside.

constexpr int SEQ = 512, BN = 1024, TT = 48;
constexpr int CH = 32;
#define LOG2E 1.44269504088896340736f
#define LN2   0.69314718055994530942f

__device__ __forceinline__ float fexp2(float x) { return __builtin_amdgcn_exp2f(x); }
__device__ __forceinline__ float flog2(float x) { return __builtin_amdgcn_logf(x); }
__device__ __forceinline__ float rlane(float v, int i) {
    return __int_as_float(__builtin_amdgcn_readlane(__float_as_int(v), i));
}

__global__ __launch_bounds__(64, 1) void crf_fwd(
    const float* __restrict__ emis, const int* __restrict__ tags,
    const int* __restrict__ mask, const float* __restrict__ start_t,
    const float* __restrict__ end_t, const float* __restrict__ trans,
    float* __restrict__ ws)
{
    __shared__ __align__(16) float ebuf[2][CH * TT];  // 2 x 6 KB

    const int lane = threadIdx.x;
    const int b   = blockIdx.x & 1023;
    const int seg = blockIdx.x >> 10;
    const int cstart = seg ? 7 : 0;
    const int cend   = seg ? 16 : 8;

    const bool jv = (lane < TT);
    const int jc = jv ? lane : (TT - 1);

    // staging offsets: 6 x (64 lanes x 16B) covers 32 rows x 48 floats
    int offs[6];
#pragma unroll
    for (int k = 0; k < 6; ++k) {
        const int g = k * 64 + lane;
        const int r = g / 12, j4 = g % 12;
        offs[k] = r * (BN * TT * 4) + j4 * 16;
    }

#define STAGE_CHUNK(cc, buf)                                                   \
    {                                                                          \
        const char* cb = (const char*)emis + ((size_t)(cc) * CH * BN + b) * (TT * 4); \
        _Pragma("unroll")                                                      \
        for (int k = 0; k < 6; ++k) {                                          \
            __builtin_amdgcn_global_load_lds(                                  \
                (const __attribute__((address_space(1))) void*)(cb + offs[k]), \
                (__attribute__((address_space(3))) void*)(&ebuf[buf][k * 256]),\
                16, 0, 0);                                                     \
        }                                                                      \
    }

    // ---- prologue ----
    STAGE_CHUNK(cstart, 0);
    const int l31 = lane & 31;
    int tgv = tags[(size_t)(cstart * CH + l31) * BN + b];
    int mkv = mask[(size_t)(cstart * CH + l31) * BN + b];

    // E = exp(trans) column jc in 48 VGPRs (trans is 9KB, L1/L2-hot)
    float E[TT];
#pragma unroll
    for (int i = 0; i < TT; ++i)
        E[i] = fexp2(trans[i * TT + jc] * LOG2E);
#pragma unroll
    for (int i = 0; i < TT; ++i)
        asm volatile("" : "+v"(E[i]));

    const float st = start_t[jc];
    const float en = end_t[jc];

    asm volatile("s_waitcnt vmcnt(0)" ::: "memory");
    __builtin_amdgcn_sched_barrier(0);

    float r, numpart;
    int la, carry_tag;
    if (seg == 0) {
        const int tag0 = tags[b];
        const float e00 = ebuf[0][jc];
        r = jv ? fexp2(fmaf(st + e00, LOG2E, -6.0f)) : 0.0f;
        la = 6;
        numpart = (lane == tag0) ? (st + e00) : 0.f;
        carry_tag = tag0;
    } else {
        r = jv ? 1.0f : 0.0f;   // warm-up init: uniform (scale irrelevant)
        la = 0;
        numpart = 0.f;
        carry_tag = 0;
    }
    float numtr = 0.f, numem = 0.f, W1 = 0.f;
    int mcount = 0;

    STAGE_CHUNK(cstart + 1, 1);
    int tgn = tags[(size_t)((cstart + 1) * CH + l31) * BN + b];
    int mkn = mask[(size_t)((cstart + 1) * CH + l31) * BN + b];

    int cur = 0;

#pragma unroll 1
    for (int c = cstart; c < cend; ++c) {
        const int tbase = c * CH;
        const float* ebc = ebuf[cur];
        const bool warm = (seg == 1) && (c == 7);

        // ---- chunk-parallel numerator + commit word (lanes 0..31 = steps) ----
        const int tmv = (lane < 32 && mkv && (tbase + lane) > 0) ? tgv : -1;
        const unsigned long long vmword = __ballot(tmv >= 0);
        int tprev = __shfl_up(tgv, 1, 64);
        if (lane == 0) tprev = carry_tag;
        if (!warm) {
            if (tmv >= 0) {
                numtr += trans[tprev * TT + tgv];
                numem += ebc[lane * TT + tgv];
            }
            mcount += __popcll(__ballot(lane < 32 && mkv));
        }
        carry_tag = __builtin_amdgcn_readlane(tgv, 31);
        la += 6 * (int)__popcll(vmword);

        // group-0 emission rows for this chunk
        float ev[8];
#pragma unroll
        for (int u = 0; u < 8; ++u) ev[u] = ebc[u * TT + jc];

        // ---- 4 groups x 8 serial steps ----
#pragma unroll 1
        for (int sc = 0; sc < 4; ++sc) {
            float emul[8];
#pragma unroll
            for (int u = 0; u < 8; ++u)
                emul[u] = fexp2(fmaf(ev[u], LOG2E, -6.0f));
            if (sc < 3) {
#pragma unroll
                for (int u = 0; u < 8; ++u)
                    ev[u] = ebc[((sc + 1) * 8 + u) * TT + jc];
            }
            const unsigned gm = (unsigned)(vmword >> (sc * 8)) & 0xFFu;
            {   // renorm: exact power-of-2 from lane 0's exponent
                const float r0 = rlane(r, 0);
                const int m = ((__float_as_int(r0) >> 23) & 0xFF) - 127;
                const float scl = __int_as_float((127 - m) << 23);
                r *= scl;
                la += m;
            }
#pragma unroll
            for (int u = 0; u < 8; ++u) {
                float q0 = 0.f, q1 = 0.f, q2 = 0.f, q3 = 0.f;
#pragma unroll
                for (int i = 0; i < TT; i += 4) {
                    q0 = fmaf(rlane(r, i),     E[i],     q0);
                    q1 = fmaf(rlane(r, i + 1), E[i + 1], q1);
                    q2 = fmaf(rlane(r, i + 2), E[i + 2], q2);
                    q3 = fmaf(rlane(r, i + 3), E[i + 3], q3);
                }
                const float q = (q0 + q1) + (q2 + q3);
                const bool commit = (gm >> u) & 1u;
                r = commit ? (q * emul[u]) : r;
            }
        }

        // ---- chunk boundary: drain staged loads, swap, stage c+2 ----
        asm volatile("s_waitcnt vmcnt(0)" ::: "memory");
        __builtin_amdgcn_sched_barrier(0);
        cur ^= 1;
        tgv = tgn; mkv = mkn;
        if (c + 2 < cend) {
            STAGE_CHUNK(c + 2, cur ^ 1);
            tgn = tags[(size_t)((c + 2) * CH + l31) * BN + b];
            mkn = mask[(size_t)((c + 2) * CH + l31) * BN + b];
        }
        if (warm) {  // boundary: capture warm-up scale, reset bookkeeping
            float sv = jv ? r : 0.f, se = sv;
#pragma unroll
            for (int d = 1; d < 64; d <<= 1)
                se += __shfl_xor(se, d, 64);
            W1 = flog2(se) * LN2;
            la = 0;
        }
    }

    // ---- tails ----
    float num = numpart + numtr + numem;
#pragma unroll
    for (int d = 1; d < 64; d <<= 1)
        num += __shfl_xor(num, d, 64);

    if (seg == 0) {
        float sv = jv ? r : 0.f, se = sv;
#pragma unroll
        for (int d = 1; d < 64; d <<= 1)
            se += __shfl_xor(se, d, 64);
        const float A = (flog2(se) + (float)la) * LN2;
        if (lane == 0) {
            ws[b] = num;
            ws[1024 + b] = A;
            ws[5120 + b] = (float)mcount;
        }
    } else {
        float sv = jv ? (r * fexp2(en * LOG2E)) : 0.f, se = sv;
#pragma unroll
        for (int d = 1; d < 64; d <<= 1)
            se += __shfl_xor(se, d, 64);
        const float B = (flog2(se) + (float)la) * LN2;
        if (lane == 0) {
            ws[2048 + b] = num;
            ws[3072 + b] = W1;
            ws[4096 + b] = B;
            ws[6144 + b] = (float)mcount;
        }
    }
#undef STAGE_CHUNK
}

__global__ __launch_bounds__(256) void reduce_mean(
    const float* __restrict__ ws, const int* __restrict__ tags,
    const float* __restrict__ end_t, float* __restrict__ out)
{
    const int tid = threadIdx.x;
    float v = 0.f;
#pragma unroll
    for (int k = 0; k < 4; ++k) {
        const int b = tid + 256 * k;
        const int mc = (int)(ws[5120 + b] + ws[6144 + b]);
        const int lt = tags[(size_t)(mc - 1) * BN + b];
        const float den = ws[1024 + b] + ws[4096 + b] - ws[3072 + b];
        v += ws[b] + ws[2048 + b] + end_t[lt] - den;
    }
#pragma unroll
    for (int d = 1; d < 64; d <<= 1)
        v += __shfl_xor(v, d, 64);
    __shared__ float acc[4];
    if ((tid & 63) == 0) acc[tid >> 6] = v;
    __syncthreads();
    if (tid == 0) out[0] = (acc[0] + acc[1] + acc[2] + acc[3]) * (1.f / 1024.f);
}

extern "C" void kernel_launch(void* const* d_in, const int* in_sizes, int n_in,
                              void* d_out, int out_size, void* d_ws, size_t ws_size,
                              hipStream_t stream)
{
    const float* emis    = (const float*)d_in[0];
    const int*   tags    = (const int*)d_in[1];
    const int*   mask    = (const int*)d_in[2];
    const float* start_t = (const float*)d_in[3];
    const float* end_t   = (const float*)d_in[4];
    const float* trans   = (const float*)d_in[5];
    float* ws  = (float*)d_ws;
    float* out = (float*)d_out;

    crf_fwd<<<dim3(2048), dim3(64), 0, stream>>>(emis, tags, mask, start_t, end_t, trans, ws);
    reduce_mean<<<dim3(1), dim3(256), 0, stream>>>(ws, tags, end_t, out);
}